// Round 6
// baseline (99.283 us; speedup 1.0000x reference)
//
#include <hip/hip_runtime.h>
#include <hip/hip_bf16.h>
#include <stdint.h>

typedef float f32x4 __attribute__((ext_vector_type(4)));
typedef short s16x8 __attribute__((ext_vector_type(8)));
typedef int   i32x4 __attribute__((ext_vector_type(4)));
typedef _Float16 f16x4 __attribute__((ext_vector_type(4)));
typedef unsigned int u32;

#define NNODES 4096
#define INC    256
#define OUTF   256
#define NEG    0.2f
#define SJ     8
#define JL     512          // NNODES / SJ
#define NIT    16           // JL / 32

__device__ __forceinline__ unsigned short f2bf(float f) {
  unsigned u = __float_as_uint(f);
  u += 0x7FFFu + ((u >> 16) & 1u);          // RNE
  return (unsigned short)(u >> 16);
}
__device__ __forceinline__ unsigned encf(float x) {
  unsigned u = __float_as_uint(x);
  return (u & 0x80000000u) ? ~u : (u | 0x80000000u);
}
__device__ __forceinline__ float decf(unsigned e) {
  unsigned u = (e & 0x80000000u) ? (e ^ 0x80000000u) : ~e;
  return __uint_as_float(u);
}

// ---------------------------------------------------------------------------
// Kernel A (unchanged from round 5): h = x @ W (f32). Tile 32n x 64c, BK=32,
// grid (4 hb, 128 nb). Writes hT (bf16 [c][n], granule-swizzled within each
// 32-n block: granule g of row c stored at g ^ ((c&3)^((c>>2)&3))), el logits
// (f32), QS packed (bf16 exp(0.2*er) << 16 | bf16 exp(er)), atomicMax of
// global er max per head.
// ---------------------------------------------------------------------------
__global__ __launch_bounds__(256) void k_feat(
    const float* __restrict__ x, const float* __restrict__ W,
    const float* __restrict__ attl, const float* __restrict__ attr,
    unsigned short* __restrict__ hT, float* __restrict__ el_t,
    u32* __restrict__ QS, unsigned* __restrict__ M_enc)
{
  __shared__ float sm[3328];
  float* xs  = sm;          // [32k][36]
  float* wsl = sm + 1152;   // [32k][68]
  const int tid = threadIdx.x;
  const int hb = blockIdx.x, nb = blockIdx.y;
  const int n0 = nb * 32, c0 = hb * 64;
  const int ty = tid >> 4, tx = tid & 15;

  float acc[2][4];
#pragma unroll
  for (int r = 0; r < 2; ++r)
#pragma unroll
    for (int j = 0; j < 4; ++j) acc[r][j] = 0.f;

  const int sxn = tid >> 3;
  const int sxk = (tid & 7) * 4;
  const int swk = tid >> 3;
  const int swc = (tid & 7) * 8;

  for (int kc = 0; kc < INC; kc += 32) {
    __syncthreads();
    {
      float4 a = *(const float4*)(x + (size_t)(n0 + sxn) * INC + kc + sxk);
      xs[(sxk + 0) * 36 + sxn] = a.x;
      xs[(sxk + 1) * 36 + sxn] = a.y;
      xs[(sxk + 2) * 36 + sxn] = a.z;
      xs[(sxk + 3) * 36 + sxn] = a.w;
      const float* wp = W + (size_t)(kc + swk) * OUTF + c0 + swc;
      *(float4*)(wsl + swk * 68 + swc)     = *(const float4*)wp;
      *(float4*)(wsl + swk * 68 + swc + 4) = *(const float4*)(wp + 4);
    }
    __syncthreads();
#pragma unroll
    for (int k = 0; k < 32; ++k) {
      float a0 = xs[k * 36 + ty * 2];
      float a1 = xs[k * 36 + ty * 2 + 1];
      float4 b = *(const float4*)(wsl + k * 68 + tx * 4);
      acc[0][0] = fmaf(a0, b.x, acc[0][0]); acc[0][1] = fmaf(a0, b.y, acc[0][1]);
      acc[0][2] = fmaf(a0, b.z, acc[0][2]); acc[0][3] = fmaf(a0, b.w, acc[0][3]);
      acc[1][0] = fmaf(a1, b.x, acc[1][0]); acc[1][1] = fmaf(a1, b.y, acc[1][1]);
      acc[1][2] = fmaf(a1, b.z, acc[1][2]); acc[1][3] = fmaf(a1, b.w, acc[1][3]);
    }
  }

  float4 al = *(const float4*)(attl + c0 + tx * 4);
  float4 ar = *(const float4*)(attr + c0 + tx * 4);
  float pl[2], pr[2];
#pragma unroll
  for (int r = 0; r < 2; ++r) {
    pl[r] = acc[r][0] * al.x + acc[r][1] * al.y + acc[r][2] * al.z + acc[r][3] * al.w;
    pr[r] = acc[r][0] * ar.x + acc[r][1] * ar.y + acc[r][2] * ar.z + acc[r][3] * ar.w;
  }
#pragma unroll
  for (int m = 1; m < 16; m <<= 1) {
#pragma unroll
    for (int r = 0; r < 2; ++r) {
      pl[r] += __shfl_xor(pl[r], m, 64);
      pr[r] += __shfl_xor(pr[r], m, 64);
    }
  }
  if (tx == 0) {
#pragma unroll
    for (int r = 0; r < 2; ++r) {
      el_t[hb * NNODES + n0 + ty * 2 + r] = pl[r];
      float q = __expf(pr[r]);
      float s = __expf(NEG * pr[r]);
      QS[hb * NNODES + n0 + ty * 2 + r] = (u32)f2bf(q) | ((u32)f2bf(s) << 16);
    }
  }
  float mx = fmaxf(pr[0], pr[1]);
  mx = fmaxf(mx, __shfl_xor(mx, 16, 64));
  mx = fmaxf(mx, __shfl_xor(mx, 32, 64));
  if ((tid & 63) == 0) atomicMax(M_enc + hb, encf(mx));

  __syncthreads();
#pragma unroll
  for (int r = 0; r < 2; ++r)
#pragma unroll
    for (int j = 0; j < 4; ++j)
      sm[(tx * 4 + j) * 33 + ty * 2 + r] = acc[r][j];
  __syncthreads();
  {
    const int c = tid >> 2, g = tid & 3;
    unsigned v[4];
#pragma unroll
    for (int i = 0; i < 4; ++i) {
      unsigned lo = f2bf(sm[c * 33 + g * 8 + 2 * i]);
      unsigned hi = f2bf(sm[c * 33 + g * 8 + 2 * i + 1]);
      v[i] = lo | (hi << 16);
    }
    const int sw = (c & 3) ^ ((c >> 2) & 3);
    unsigned short* dst = hT + (size_t)(c0 + c) * NNODES + n0 + ((g ^ sw) * 8);
    *(uint4*)dst = make_uint4(v[0], v[1], v[2], v[3]);
  }
}

// ---------------------------------------------------------------------------
// Kernel B: fused masked-softmax + PV. Block = 4 waves = 4 heads sharing
// 32 i-rows; wave = 2 i-chunks x 1 head (B-frags reused across chunks).
// hT: 4-slot LDS ring (16KB/slot, all 256 c), filled depth-3 ahead with
// global_load_lds; adj: register ring-4, direct HBM loads depth-3;
// QS: staged once in LDS (8KB, broadcast reads). FULLY UNROLLED 16
// iterations: all slots/offsets are immediates, no rotation movs.
// Per iter: [vmcnt(16) -> retire set(k)] [s_barrier] [issue set(k+3)]
// [ds_read + compute]. Per-iter VMEM = 4 fills + 4 adj = 8, uniform.
// Partials: nump in f16 (halves k_div traffic), den f32 via ones-MFMA.
// ---------------------------------------------------------------------------
__global__ __launch_bounds__(256, 2) void k_gat(
    const int* __restrict__ adj, const unsigned short* __restrict__ hT,
    const float* __restrict__ el_t, const u32* __restrict__ QS,
    const unsigned* __restrict__ M_enc,
    _Float16* __restrict__ nump, float* __restrict__ denp)
{
  __shared__ __align__(16) unsigned short hbuf[4][8192];  // 4 x 16KB [256 c][32 j]
  __shared__ __align__(16) u32 qsb[4 * JL];               // 8KB [4 h][JL j]

  const int tid = threadIdx.x;
  const int wid = tid >> 6, lane = tid & 63;
  const int l15 = lane & 15, lg = lane >> 4;
  const int h  = wid;                      // one head per wave
  const int i0 = blockIdx.x * 32;
  const int js = blockIdx.y;
  const int j0 = js * JL;
  const int sw_l = (l15 & 3) ^ ((l15 >> 2) & 3);

  // P,R per i-chunk (computed first: drains el_t loads before fill issue)
  float P[2], R[2];
#pragma unroll
  for (int ic = 0; ic < 2; ++ic) {
    float el  = el_t[h * NNODES + i0 + ic * 16 + l15];
    float M   = decf(M_enc[h]);
    float sE  = el + M;
    float mih = fmaxf(sE, NEG * sE);       // >= every masked score for row i
    P[ic] = __expf(el - mih);
    R[ic] = __expf(NEG * el - mih);
  }

  // fill sources
  const unsigned short* hsb = hT + (size_t)(wid * 64 + (lane >> 2)) * NNODES + j0 + (lane & 3) * 8;
  const unsigned short* hs0 = hsb;
  const unsigned short* hs1 = hsb + (size_t)16 * NNODES;
  const unsigned short* hs2 = hsb + (size_t)32 * NNODES;
  const unsigned short* hs3 = hsb + (size_t)48 * NNODES;
  const u32* qsrc = QS + (size_t)wid * NNODES + j0 + lane * 4;
  const int* ap0 = adj + (size_t)(i0 + l15) * NNODES + j0 + lg * 8;
  const int* ap1 = adj + (size_t)(i0 + 16 + l15) * NNODES + j0 + lg * 8;

  f32x4 acc[2][4];
  f32x4 accd[2];
#pragma unroll
  for (int ic = 0; ic < 2; ++ic) {
    accd[ic] = (f32x4){0.f, 0.f, 0.f, 0.f};
#pragma unroll
    for (int c = 0; c < 4; ++c) acc[ic][c] = (f32x4){0.f, 0.f, 0.f, 0.f};
  }
  s16x8 ones;
#pragma unroll
  for (int e = 0; e < 8; ++e) ones[e] = (short)0x3F80;  // bf16 1.0

  i32x4 aR[4][2][2];   // ring-4 x 2 ic x 2 halves; all indices compile-time

#define ISSUE_SET(T)                                                             \
  do {                                                                           \
    __builtin_amdgcn_global_load_lds(hs0 + (T) * 32, &hbuf[(T) & 3][wid * 2048 +    0], 16, 0, 0); \
    __builtin_amdgcn_global_load_lds(hs1 + (T) * 32, &hbuf[(T) & 3][wid * 2048 +  512], 16, 0, 0); \
    __builtin_amdgcn_global_load_lds(hs2 + (T) * 32, &hbuf[(T) & 3][wid * 2048 + 1024], 16, 0, 0); \
    __builtin_amdgcn_global_load_lds(hs3 + (T) * 32, &hbuf[(T) & 3][wid * 2048 + 1536], 16, 0, 0); \
    aR[(T) & 3][0][0] = *(const i32x4*)(ap0 + (T) * 32);                         \
    aR[(T) & 3][0][1] = *(const i32x4*)(ap0 + (T) * 32 + 4);                     \
    aR[(T) & 3][1][0] = *(const i32x4*)(ap1 + (T) * 32);                         \
    aR[(T) & 3][1][1] = *(const i32x4*)(ap1 + (T) * 32 + 4);                     \
  } while (0)

  // prologue: QS (2 loads) + sets 0,1,2  -> 26 outstanding VMEM
  __builtin_amdgcn_global_load_lds(qsrc,       &qsb[wid * 512],       16, 0, 0);
  __builtin_amdgcn_global_load_lds(qsrc + 256, &qsb[wid * 512 + 256], 16, 0, 0);
  ISSUE_SET(0);
  ISSUE_SET(1);
  ISSUE_SET(2);

#define STEP(K, VNSTR, DOISSUE)                                                  \
  {                                                                              \
    asm volatile("s_waitcnt vmcnt(" VNSTR ")" ::: "memory");                     \
    __builtin_amdgcn_s_barrier();                                                \
    if (DOISSUE) ISSUE_SET((K) + 3);                                             \
    const unsigned short* lb = &hbuf[(K) & 3][(h * 64 + l15) * 32 + ((lg ^ sw_l) * 8)]; \
    s16x8 b0 = *(const s16x8*)(lb);                                              \
    s16x8 b1 = *(const s16x8*)(lb + 512);                                        \
    s16x8 b2 = *(const s16x8*)(lb + 1024);                                       \
    s16x8 b3 = *(const s16x8*)(lb + 1536);                                       \
    i32x4 qv0 = *(const i32x4*)(qsb + h * JL + (K) * 32 + lg * 8);               \
    i32x4 qv1 = *(const i32x4*)(qsb + h * JL + (K) * 32 + lg * 8 + 4);           \
    _Pragma("unroll")                                                            \
    for (int ic = 0; ic < 2; ++ic) {                                             \
      const i32x4 a0 = aR[(K) & 3][ic][0];                                       \
      const i32x4 a1 = aR[(K) & 3][ic][1];                                       \
      float w[8];                                                                \
      _Pragma("unroll")                                                          \
      for (int e = 0; e < 4; ++e) {                                              \
        u32 m0 = (a0[e] > 0) ? (u32)qv0[e] : 0u;                                 \
        u32 m1 = (a1[e] > 0) ? (u32)qv1[e] : 0u;                                 \
        float qq0 = __uint_as_float(m0 << 16);                                   \
        float ss0 = __uint_as_float(m0 & 0xffff0000u);                           \
        float qq1 = __uint_as_float(m1 << 16);                                   \
        float ss1 = __uint_as_float(m1 & 0xffff0000u);                           \
        w[e]     = fmaxf(P[ic] * qq0, R[ic] * ss0);                              \
        w[e + 4] = fmaxf(P[ic] * qq1, R[ic] * ss1);                              \
      }                                                                          \
      union { u32 uu[4]; s16x8 v; } af;                                          \
      _Pragma("unroll")                                                          \
      for (int p = 0; p < 4; ++p)                                                \
        asm("v_cvt_pk_bf16_f32 %0, %1, %2" : "=v"(af.uu[p]) : "v"(w[2 * p]), "v"(w[2 * p + 1])); \
      acc[ic][0] = __builtin_amdgcn_mfma_f32_16x16x32_bf16(af.v, b0,   acc[ic][0], 0, 0, 0); \
      acc[ic][1] = __builtin_amdgcn_mfma_f32_16x16x32_bf16(af.v, b1,   acc[ic][1], 0, 0, 0); \
      acc[ic][2] = __builtin_amdgcn_mfma_f32_16x16x32_bf16(af.v, b2,   acc[ic][2], 0, 0, 0); \
      acc[ic][3] = __builtin_amdgcn_mfma_f32_16x16x32_bf16(af.v, b3,   acc[ic][3], 0, 0, 0); \
      accd[ic]   = __builtin_amdgcn_mfma_f32_16x16x32_bf16(af.v, ones, accd[ic],   0, 0, 0); \
    }                                                                            \
  }

  STEP(0,  "16", 1)  STEP(1,  "16", 1)  STEP(2,  "16", 1)  STEP(3,  "16", 1)
  STEP(4,  "16", 1)  STEP(5,  "16", 1)  STEP(6,  "16", 1)  STEP(7,  "16", 1)
  STEP(8,  "16", 1)  STEP(9,  "16", 1)  STEP(10, "16", 1)  STEP(11, "16", 1)
  STEP(12, "16", 1)  STEP(13, "16", 0)  STEP(14, "8",  0)  STEP(15, "0",  0)

#undef STEP
#undef ISSUE_SET

  // C/D layout: col = lane&15, row = (lane>>4)*4 + reg
#pragma unroll
  for (int ic = 0; ic < 2; ++ic) {
    const int orow = i0 + ic * 16 + lg * 4;
    _Float16* np = nump + ((size_t)js * NNODES + orow) * OUTF + h * 64 + l15;
#pragma unroll
    for (int c = 0; c < 4; ++c)
#pragma unroll
      for (int r = 0; r < 4; ++r)
        np[r * OUTF + c * 16] = (_Float16)acc[ic][c][r];
    if (l15 == 0) {
      float* dp = denp + ((size_t)js * NNODES + orow) * 4 + h;
#pragma unroll
      for (int r = 0; r < 4; ++r) dp[r * 4] = accd[ic][r];
    }
  }
}

// ---------------------------------------------------------------------------
// Kernel C: sum f16 j-split partials, divide by den, add bias.
// ---------------------------------------------------------------------------
__global__ __launch_bounds__(256) void k_div(
    const _Float16* __restrict__ nump, const float* __restrict__ denp,
    const float* __restrict__ bias, float* __restrict__ out)
{
  const int q  = blockIdx.x * 256 + threadIdx.x;  // float4 index
  const int n  = q >> 6;
  const int c4 = (q & 63) * 4;
  const int h  = c4 >> 6;
  f32x4 s = {0.f, 0.f, 0.f, 0.f};
  float d = 0.f;
#pragma unroll
  for (int t = 0; t < SJ; ++t) {
    f16x4 v = *(const f16x4*)(nump + ((size_t)t * NNODES + n) * OUTF + c4);
    s[0] += (float)v[0]; s[1] += (float)v[1];
    s[2] += (float)v[2]; s[3] += (float)v[3];
    d += denp[((size_t)t * NNODES + n) * 4 + h];
  }
  f32x4 b = *(const f32x4*)(bias + c4);
  float r = __builtin_amdgcn_rcpf(d);
  f32x4 o = s * r + b;
  *(f32x4*)(out + (size_t)n * OUTF + c4) = o;
}

extern "C" void kernel_launch(void* const* d_in, const int* in_sizes, int n_in,
                              void* d_out, int out_size, void* d_ws, size_t ws_size,
                              hipStream_t stream)
{
  const float* x    = (const float*)d_in[0];
  const int*   adj  = (const int*)d_in[1];
  const float* W    = (const float*)d_in[2];
  const float* attl = (const float*)d_in[3];
  const float* attr = (const float*)d_in[4];
  const float* bias = (const float*)d_in[5];
  float* out = (float*)d_out;
  char*  ws  = (char*)d_ws;

  // workspace layout (total ~19MB)
  unsigned short* hT  = (unsigned short*)ws;                        // 2 MB
  float*     el_t  = (float*)(ws + (2u << 20));                     // 64 KB
  u32*       QS    = (u32*)(ws + (2u << 20) + (64u << 10));         // 64 KB
  unsigned*  M_enc = (unsigned*)(ws + (2u << 20) + (128u << 10));   // 16 B
  float*     denp  = (float*)(ws + (2u << 20) + (192u << 10));      // 512 KB
  _Float16*  nump  = (_Float16*)(ws + (3u << 20));                  // 16 MB (SJ x 2MB f16)

  hipMemsetAsync(M_enc, 0, 16, stream);
  k_feat<<<dim3(4, 128), 256, 0, stream>>>(x, W, attl, attr, hT, el_t, QS, M_enc);
  k_gat<<<dim3(128, SJ), 256, 0, stream>>>(adj, hT, el_t, QS, M_enc, nump, denp);
  k_div<<<dim3(1024), 256, 0, stream>>>(nump, denp, bias, out);
}

// Round 7
// 69.050 us; speedup vs baseline: 1.4378x; 1.4378x over previous
//
#include <hip/hip_runtime.h>
#include <hip/hip_bf16.h>
#include <stdint.h>

typedef float f32x4 __attribute__((ext_vector_type(4)));
typedef short s16x8 __attribute__((ext_vector_type(8)));
typedef int   i32x4 __attribute__((ext_vector_type(4)));
typedef _Float16 f16x4 __attribute__((ext_vector_type(4)));
typedef unsigned int u32;

#define NNODES 4096
#define INC    256
#define OUTF   256
#define NEG    0.2f
#define SJ     8
#define JL     512          // j per k_gat block (2 phases of 256)

__device__ __forceinline__ unsigned short f2bf(float f) {
  unsigned u = __float_as_uint(f);
  u += 0x7FFFu + ((u >> 16) & 1u);          // RNE
  return (unsigned short)(u >> 16);
}
__device__ __forceinline__ unsigned encf(float x) {
  unsigned u = __float_as_uint(x);
  return (u & 0x80000000u) ? ~u : (u | 0x80000000u);
}
__device__ __forceinline__ float decf(unsigned e) {
  unsigned u = (e & 0x80000000u) ? (e ^ 0x80000000u) : ~e;
  return __uint_as_float(u);
}

// ---------------------------------------------------------------------------
// Kernel A: h = x @ W (f32). Block = 64n x 64c, 256 thr, thread = 4n x 4c.
// Stage FULL x-slab (64n x 256k, row-padded) + W-slab (256k x 64c) into LDS
// once (129KB), ONE barrier, then barrier-free K=256 loop of pure
// ds_read_b128 + FMA (16 FMA : 2 LDS-vec reads per k). Grid (4 hb, 64 nb) =
// 256 blocks = 1/CU. Epilogue: el/er logits via tx-shuffle reduce, QS packed
// exp pair, atomicMax er-max, transpose->bf16 hT store (granule-swizzled
// within each 32-n block: granule g of row c at g ^ ((c&3)^((c>>2)&3))).
// ---------------------------------------------------------------------------
__global__ __launch_bounds__(256) void k_feat(
    const float* __restrict__ x, const float* __restrict__ W,
    const float* __restrict__ attl, const float* __restrict__ attr,
    unsigned short* __restrict__ hT, float* __restrict__ el_t,
    u32* __restrict__ QS, unsigned* __restrict__ M_enc)
{
  __shared__ float smbuf[33024];
  float* xs  = smbuf;            // [64 n][260]: 1KB data + 16B pad per row
  float* wsl = smbuf + 16640;    // [256 k][64 c], unpadded (tx-spread reads)
  const int tid  = threadIdx.x;
  const int lane = tid & 63, wid = tid >> 6;
  const int hb = blockIdx.x, nb = blockIdx.y;
  const int n0 = nb * 64, c0 = hb * 64;
  const int ty = tid >> 4, tx = tid & 15;

  // stage x: 64 rows x 1KB = 16 instrs/wave (dest linear per row, pad skipped)
#pragma unroll
  for (int q = 0; q < 16; ++q) {
    const int n = wid * 16 + q;
    __builtin_amdgcn_global_load_lds(x + (size_t)(n0 + n) * INC + lane * 4,
                                     xs + n * 260, 16, 0, 0);
  }
  // stage W: 256 rows x 256B -> 64 x 1KB instrs (4 k-rows each), 16/wave
#pragma unroll
  for (int q = 0; q < 16; ++q) {
    const int kb = (wid * 16 + q) * 4;
    __builtin_amdgcn_global_load_lds(
        W + (size_t)(kb + (lane >> 4)) * OUTF + c0 + (lane & 15) * 4,
        wsl + kb * 64, 16, 0, 0);
  }
  __syncthreads();

  f32x4 acc[4];   // acc[r] = 4 c-outputs for n-row r
#pragma unroll
  for (int r = 0; r < 4; ++r) acc[r] = (f32x4){0.f, 0.f, 0.f, 0.f};

#pragma unroll 4
  for (int k4 = 0; k4 < 64; ++k4) {
    f32x4 a[4], b[4];
#pragma unroll
    for (int r = 0; r < 4; ++r)
      a[r] = *(const f32x4*)(xs + (ty * 4 + r) * 260 + k4 * 4);
#pragma unroll
    for (int kk = 0; kk < 4; ++kk)
      b[kk] = *(const f32x4*)(wsl + (k4 * 4 + kk) * 64 + tx * 4);
#pragma unroll
    for (int r = 0; r < 4; ++r)
#pragma unroll
      for (int kk = 0; kk < 4; ++kk)
        acc[r] += a[r][kk] * b[kk];
  }

  // logits for head hb (this block covers all 64 channels of the head)
  f32x4 al = *(const f32x4*)(attl + c0 + tx * 4);
  f32x4 ar = *(const f32x4*)(attr + c0 + tx * 4);
  float pl[4], pr[4];
#pragma unroll
  for (int r = 0; r < 4; ++r) {
    pl[r] = acc[r][0] * al[0] + acc[r][1] * al[1] + acc[r][2] * al[2] + acc[r][3] * al[3];
    pr[r] = acc[r][0] * ar[0] + acc[r][1] * ar[1] + acc[r][2] * ar[2] + acc[r][3] * ar[3];
  }
#pragma unroll
  for (int m = 1; m < 16; m <<= 1) {
#pragma unroll
    for (int r = 0; r < 4; ++r) {
      pl[r] += __shfl_xor(pl[r], m, 64);
      pr[r] += __shfl_xor(pr[r], m, 64);
    }
  }
  if (tx == 0) {
#pragma unroll
    for (int r = 0; r < 4; ++r) {
      el_t[hb * NNODES + n0 + ty * 4 + r] = pl[r];
      float q = __expf(pr[r]);
      float s = __expf(NEG * pr[r]);
      QS[hb * NNODES + n0 + ty * 4 + r] = (u32)f2bf(q) | ((u32)f2bf(s) << 16);
    }
  }
  float mx = fmaxf(fmaxf(pr[0], pr[1]), fmaxf(pr[2], pr[3]));
  mx = fmaxf(mx, __shfl_xor(mx, 16, 64));
  mx = fmaxf(mx, __shfl_xor(mx, 32, 64));
  if (lane == 0) atomicMax(M_enc + hb, encf(mx));

  // transpose via LDS (reuse xs region) and store bf16 hT, swizzled
  __syncthreads();
  float* smT = smbuf;  // [64 c][65]
#pragma unroll
  for (int r = 0; r < 4; ++r)
#pragma unroll
    for (int j = 0; j < 4; ++j)
      smT[(tx * 4 + j) * 65 + ty * 4 + r] = acc[r][j];
  __syncthreads();
  {
    const int c = tid >> 2, g0 = tid & 3;
    const int sw = (c & 3) ^ ((c >> 2) & 3);
#pragma unroll
    for (int t = 0; t < 2; ++t) {
      const int gg = g0 + t * 4;           // granule of 8 n within 64-n tile
      unsigned v[4];
#pragma unroll
      for (int i = 0; i < 4; ++i) {
        unsigned lo = f2bf(smT[c * 65 + gg * 8 + 2 * i]);
        unsigned hi = f2bf(smT[c * 65 + gg * 8 + 2 * i + 1]);
        v[i] = lo | (hi << 16);
      }
      unsigned short* dst = hT + (size_t)(c0 + c) * NNODES + n0 + (gg >> 2) * 32
                            + (((gg & 3) ^ sw) * 8);
      *(uint4*)dst = make_uint4(v[0], v[1], v[2], v[3]);
    }
  }
}

// ---------------------------------------------------------------------------
// Kernel B: fused masked-softmax + PV. Block = 512 thr = 8 waves, each wave
// = 16 i-rows x ALL 4 heads. j is block-resident: the block owns JL=512 j,
// staged as 2 slabs of 256 j x 256 channels (128KB LDS) -- 4 barriers per
// block TOTAL, no per-chunk sync. Within a phase: 8 chunks of 32 j, fully
// unrolled, adj register-prefetched 1 chunk ahead (SSA renames only),
// b-frags + QS from static LDS. w = max(P_i*Q_j, R_i*S_j) exact
// leaky-softmax factorization; den via ones-MFMA. Partials f16.
// ---------------------------------------------------------------------------
__global__ __launch_bounds__(512, 2) void k_gat(
    const int* __restrict__ adj, const unsigned short* __restrict__ hT,
    const float* __restrict__ el_t, const u32* __restrict__ QS,
    const unsigned* __restrict__ M_enc,
    _Float16* __restrict__ nump, float* __restrict__ denp)
{
  __shared__ __align__(16) unsigned short hbuf[256 * 256];  // 128KB [256 c][256 j]
  __shared__ __align__(16) u32 qsb[4 * JL];                 // 8KB [4 h][512 j]

  const int tid = threadIdx.x;
  const int wid = tid >> 6, lane = tid & 63;
  const int l15 = lane & 15, lg = lane >> 4;
  const int i0 = blockIdx.x * 128 + wid * 16;
  const int js = blockIdx.y;
  const int j0 = js * JL;
  const int sw_l = (l15 & 3) ^ ((l15 >> 2) & 3);

  float P[4], R[4];
#pragma unroll
  for (int h = 0; h < 4; ++h) {
    float el  = el_t[h * NNODES + i0 + l15];
    float M   = decf(M_enc[h]);
    float sE  = el + M;
    float mih = fmaxf(sE, NEG * sE);   // >= every masked score for row i
    P[h] = __expf(el - mih);
    R[h] = __expf(NEG * el - mih);
  }

  // QS staged once (both phases): 8 waves x 1KB
  __builtin_amdgcn_global_load_lds(
      QS + (size_t)(wid >> 1) * NNODES + j0 + (wid & 1) * 256 + lane * 4,
      qsb + (wid >> 1) * JL + (wid & 1) * 256, 16, 0, 0);

  const int* asrc = adj + (size_t)(i0 + l15) * NNODES + j0 + lg * 8;

  f32x4 acc[4][4];
  f32x4 accd[4];
#pragma unroll
  for (int h = 0; h < 4; ++h) {
    accd[h] = (f32x4){0.f, 0.f, 0.f, 0.f};
#pragma unroll
    for (int c = 0; c < 4; ++c) acc[h][c] = (f32x4){0.f, 0.f, 0.f, 0.f};
  }
  s16x8 ones;
#pragma unroll
  for (int e = 0; e < 8; ++e) ones[e] = (short)0x3F80;  // bf16 1.0

  // stage hT slab for phase p: 16 x 1KB instrs/wave (2 c-rows each)
#define STAGE(p)                                                                 \
  do {                                                                           \
    _Pragma("unroll")                                                            \
    for (int q = 0; q < 16; ++q) {                                               \
      const int c2 = wid * 32 + q * 2;                                           \
      __builtin_amdgcn_global_load_lds(                                          \
          hT + (size_t)(c2 + (lane >> 5)) * NNODES + j0 + (p) * 256 + (lane & 31) * 8, \
          hbuf + c2 * 256, 16, 0, 0);                                            \
    }                                                                            \
  } while (0)

  STAGE(0);

#pragma unroll
  for (int p = 0; p < 2; ++p) {
    if (p == 1) {
      __syncthreads();          // all phase-0 LDS reads done before overwrite
      STAGE(1);
    }
    // prefetch adj chunk 0 of this phase (overlaps staging latency)
    i32x4 a0 = *(const i32x4*)(asrc + p * 256);
    i32x4 a1 = *(const i32x4*)(asrc + p * 256 + 4);
    __syncthreads();            // slab + QS ready (vmcnt/lgkm drain + barrier)

#pragma unroll
    for (int K = 0; K < 8; ++K) {
      const int nK = (K < 7) ? (K + 1) : 7;
      i32x4 na0 = *(const i32x4*)(asrc + p * 256 + nK * 32);
      i32x4 na1 = *(const i32x4*)(asrc + p * 256 + nK * 32 + 4);

#pragma unroll
      for (int h = 0; h < 4; ++h) {
        const unsigned short* lb =
            hbuf + (h * 64 + l15) * 256 + K * 32 + ((lg ^ sw_l) * 8);
        s16x8 b0 = *(const s16x8*)(lb);
        s16x8 b1 = *(const s16x8*)(lb + 16 * 256);
        s16x8 b2 = *(const s16x8*)(lb + 32 * 256);
        s16x8 b3 = *(const s16x8*)(lb + 48 * 256);
        const u32* qrow = qsb + h * JL + p * 256 + K * 32 + lg * 8;
        i32x4 q0 = *(const i32x4*)(qrow);
        i32x4 q1 = *(const i32x4*)(qrow + 4);

        float w[8];
#pragma unroll
        for (int e = 0; e < 4; ++e) {
          u32 m0 = (a0[e] > 0) ? (u32)q0[e] : 0u;
          u32 m1 = (a1[e] > 0) ? (u32)q1[e] : 0u;
          float qq0 = __uint_as_float(m0 << 16);
          float ss0 = __uint_as_float(m0 & 0xffff0000u);
          float qq1 = __uint_as_float(m1 << 16);
          float ss1 = __uint_as_float(m1 & 0xffff0000u);
          w[e]     = fmaxf(P[h] * qq0, R[h] * ss0);
          w[e + 4] = fmaxf(P[h] * qq1, R[h] * ss1);
        }
        union { u32 uu[4]; s16x8 v; } af;
#pragma unroll
        for (int pp = 0; pp < 4; ++pp)
          asm("v_cvt_pk_bf16_f32 %0, %1, %2"
              : "=v"(af.uu[pp]) : "v"(w[2 * pp]), "v"(w[2 * pp + 1]));

        acc[h][0] = __builtin_amdgcn_mfma_f32_16x16x32_bf16(af.v, b0,   acc[h][0], 0, 0, 0);
        acc[h][1] = __builtin_amdgcn_mfma_f32_16x16x32_bf16(af.v, b1,   acc[h][1], 0, 0, 0);
        acc[h][2] = __builtin_amdgcn_mfma_f32_16x16x32_bf16(af.v, b2,   acc[h][2], 0, 0, 0);
        acc[h][3] = __builtin_amdgcn_mfma_f32_16x16x32_bf16(af.v, b3,   acc[h][3], 0, 0, 0);
        accd[h]   = __builtin_amdgcn_mfma_f32_16x16x32_bf16(af.v, ones, accd[h],   0, 0, 0);
      }
      a0 = na0; a1 = na1;
    }
  }
#undef STAGE

  // C/D layout: col = lane&15, row = (lane>>4)*4 + reg
  const int orow = i0 + lg * 4;
#pragma unroll
  for (int h = 0; h < 4; ++h) {
    _Float16* np = nump + ((size_t)js * NNODES + orow) * OUTF + h * 64 + l15;
#pragma unroll
    for (int c = 0; c < 4; ++c)
#pragma unroll
      for (int r = 0; r < 4; ++r)
        np[r * OUTF + c * 16] = (_Float16)acc[h][c][r];
  }
  if (l15 == 0) {
    float* dp = denp + ((size_t)js * NNODES + orow) * 4;
#pragma unroll
    for (int h = 0; h < 4; ++h)
#pragma unroll
      for (int r = 0; r < 4; ++r) dp[r * 4 + h] = accd[h][r];
  }
}

// ---------------------------------------------------------------------------
// Kernel C: sum f16 j-split partials, divide by den, add bias.
// ---------------------------------------------------------------------------
__global__ __launch_bounds__(256) void k_div(
    const _Float16* __restrict__ nump, const float* __restrict__ denp,
    const float* __restrict__ bias, float* __restrict__ out)
{
  const int q  = blockIdx.x * 256 + threadIdx.x;  // float4 index
  const int n  = q >> 6;
  const int c4 = (q & 63) * 4;
  const int h  = c4 >> 6;
  f32x4 s = {0.f, 0.f, 0.f, 0.f};
  float d = 0.f;
#pragma unroll
  for (int t = 0; t < SJ; ++t) {
    f16x4 v = *(const f16x4*)(nump + ((size_t)t * NNODES + n) * OUTF + c4);
    s[0] += (float)v[0]; s[1] += (float)v[1];
    s[2] += (float)v[2]; s[3] += (float)v[3];
    d += denp[((size_t)t * NNODES + n) * 4 + h];
  }
  f32x4 b = *(const f32x4*)(bias + c4);
  float r = __builtin_amdgcn_rcpf(d);
  f32x4 o = s * r + b;
  *(f32x4*)(out + (size_t)n * OUTF + c4) = o;
}

extern "C" void kernel_launch(void* const* d_in, const int* in_sizes, int n_in,
                              void* d_out, int out_size, void* d_ws, size_t ws_size,
                              hipStream_t stream)
{
  const float* x    = (const float*)d_in[0];
  const int*   adj  = (const int*)d_in[1];
  const float* W    = (const float*)d_in[2];
  const float* attl = (const float*)d_in[3];
  const float* attr = (const float*)d_in[4];
  const float* bias = (const float*)d_in[5];
  float* out = (float*)d_out;
  char*  ws  = (char*)d_ws;

  // workspace layout (~19MB)
  unsigned short* hT  = (unsigned short*)ws;                        // 2 MB
  float*     el_t  = (float*)(ws + (2u << 20));                     // 64 KB
  u32*       QS    = (u32*)(ws + (2u << 20) + (64u << 10));         // 64 KB
  unsigned*  M_enc = (unsigned*)(ws + (2u << 20) + (128u << 10));   // 16 B
  float*     denp  = (float*)(ws + (2u << 20) + (192u << 10));      // 512 KB
  _Float16*  nump  = (_Float16*)(ws + (3u << 20));                  // 16 MB

  hipMemsetAsync(M_enc, 0, 16, stream);
  k_feat<<<dim3(4, 64), 256, 0, stream>>>(x, W, attl, attr, hT, el_t, QS, M_enc);
  k_gat<<<dim3(32, SJ), 512, 0, stream>>>(adj, hT, el_t, QS, M_enc, nump, denp);
  k_div<<<dim3(1024), 256, 0, stream>>>(nump, denp, bias, out);
}

// Round 11
// 68.578 us; speedup vs baseline: 1.4477x; 1.0069x over previous
//
#include <hip/hip_runtime.h>
#include <hip/hip_bf16.h>
#include <stdint.h>

typedef float f32x4 __attribute__((ext_vector_type(4)));
typedef short s16x8 __attribute__((ext_vector_type(8)));
typedef int   i32x4 __attribute__((ext_vector_type(4)));
typedef _Float16 f16x4 __attribute__((ext_vector_type(4)));
typedef unsigned int u32;

#define NNODES 4096
#define INC    256
#define OUTF   256
#define NEG    0.2f
#define SJ     8
#define JL     512          // j per k_gat block (2 phases of 256)

__device__ __forceinline__ unsigned short f2bf(float f) {
  unsigned u = __float_as_uint(f);
  u += 0x7FFFu + ((u >> 16) & 1u);          // RNE
  return (unsigned short)(u >> 16);
}
__device__ __forceinline__ unsigned encf(float x) {
  unsigned u = __float_as_uint(x);
  return (u & 0x80000000u) ? ~u : (u | 0x80000000u);
}
__device__ __forceinline__ float decf(unsigned e) {
  unsigned u = (e & 0x80000000u) ? (e ^ 0x80000000u) : ~e;
  return __uint_as_float(u);
}

// ---------------------------------------------------------------------------
// Kernel A (round-7 verbatim except hT swizzle): h = x @ W (f32). Block =
// 64n x 64c, 256 thr, thread = 4n x 4c. Stage full x-slab + W-slab in LDS
// once (129KB), one barrier, barrier-free K=256 loop. Grid (4 hb, 64 nb).
// Epilogue: el/er logits, QS packed exp pair, atomicMax er-max, transpose ->
// bf16 hT store. CHANGED: granule gg (8 n) of each 64-n tile stored at
// gg ^ (c&7)  (3-bit XOR swizzle; was 2-bit within 32-n blocks).
// ---------------------------------------------------------------------------
__global__ __launch_bounds__(256) void k_feat(
    const float* __restrict__ x, const float* __restrict__ W,
    const float* __restrict__ attl, const float* __restrict__ attr,
    unsigned short* __restrict__ hT, float* __restrict__ el_t,
    u32* __restrict__ QS, unsigned* __restrict__ M_enc)
{
  __shared__ float smbuf[33024];
  float* xs  = smbuf;            // [64 n][260]: 1KB data + 16B pad per row
  float* wsl = smbuf + 16640;    // [256 k][64 c]
  const int tid  = threadIdx.x;
  const int lane = tid & 63, wid = tid >> 6;
  const int hb = blockIdx.x, nb = blockIdx.y;
  const int n0 = nb * 64, c0 = hb * 64;
  const int ty = tid >> 4, tx = tid & 15;

#pragma unroll
  for (int q = 0; q < 16; ++q) {
    const int n = wid * 16 + q;
    __builtin_amdgcn_global_load_lds(x + (size_t)(n0 + n) * INC + lane * 4,
                                     xs + n * 260, 16, 0, 0);
  }
#pragma unroll
  for (int q = 0; q < 16; ++q) {
    const int kb = (wid * 16 + q) * 4;
    __builtin_amdgcn_global_load_lds(
        W + (size_t)(kb + (lane >> 4)) * OUTF + c0 + (lane & 15) * 4,
        wsl + kb * 64, 16, 0, 0);
  }
  __syncthreads();

  f32x4 acc[4];
#pragma unroll
  for (int r = 0; r < 4; ++r) acc[r] = (f32x4){0.f, 0.f, 0.f, 0.f};

#pragma unroll 4
  for (int k4 = 0; k4 < 64; ++k4) {
    f32x4 a[4], b[4];
#pragma unroll
    for (int r = 0; r < 4; ++r)
      a[r] = *(const f32x4*)(xs + (ty * 4 + r) * 260 + k4 * 4);
#pragma unroll
    for (int kk = 0; kk < 4; ++kk)
      b[kk] = *(const f32x4*)(wsl + (k4 * 4 + kk) * 64 + tx * 4);
#pragma unroll
    for (int r = 0; r < 4; ++r)
#pragma unroll
      for (int kk = 0; kk < 4; ++kk)
        acc[r] += a[r][kk] * b[kk];
  }

  f32x4 al = *(const f32x4*)(attl + c0 + tx * 4);
  f32x4 ar = *(const f32x4*)(attr + c0 + tx * 4);
  float pl[4], pr[4];
#pragma unroll
  for (int r = 0; r < 4; ++r) {
    pl[r] = acc[r][0] * al[0] + acc[r][1] * al[1] + acc[r][2] * al[2] + acc[r][3] * al[3];
    pr[r] = acc[r][0] * ar[0] + acc[r][1] * ar[1] + acc[r][2] * ar[2] + acc[r][3] * ar[3];
  }
#pragma unroll
  for (int m = 1; m < 16; m <<= 1) {
#pragma unroll
    for (int r = 0; r < 4; ++r) {
      pl[r] += __shfl_xor(pl[r], m, 64);
      pr[r] += __shfl_xor(pr[r], m, 64);
    }
  }
  if (tx == 0) {
#pragma unroll
    for (int r = 0; r < 4; ++r) {
      el_t[hb * NNODES + n0 + ty * 4 + r] = pl[r];
      float q = __expf(pr[r]);
      float s = __expf(NEG * pr[r]);
      QS[hb * NNODES + n0 + ty * 4 + r] = (u32)f2bf(q) | ((u32)f2bf(s) << 16);
    }
  }
  float mx = fmaxf(fmaxf(pr[0], pr[1]), fmaxf(pr[2], pr[3]));
  mx = fmaxf(mx, __shfl_xor(mx, 16, 64));
  mx = fmaxf(mx, __shfl_xor(mx, 32, 64));
  if (lane == 0) atomicMax(M_enc + hb, encf(mx));

  // transpose via LDS (reuse xs region) and store bf16 hT, 8-way swizzled
  __syncthreads();
  float* smT = smbuf;  // [64 c][65]
#pragma unroll
  for (int r = 0; r < 4; ++r)
#pragma unroll
    for (int j = 0; j < 4; ++j)
      smT[(tx * 4 + j) * 65 + ty * 4 + r] = acc[r][j];
  __syncthreads();
  {
    const int c = tid >> 2, g0 = tid & 3;
    const int key = c & 7;                 // (c0+c)&7 == c&7 (c0 mult of 64)
#pragma unroll
    for (int t = 0; t < 2; ++t) {
      const int gg = g0 + t * 4;           // granule of 8 n within 64-n tile
      unsigned v[4];
#pragma unroll
      for (int i = 0; i < 4; ++i) {
        unsigned lo = f2bf(smT[c * 65 + gg * 8 + 2 * i]);
        unsigned hi = f2bf(smT[c * 65 + gg * 8 + 2 * i + 1]);
        v[i] = lo | (hi << 16);
      }
      unsigned short* dst = hT + (size_t)(c0 + c) * NNODES + n0 + ((gg ^ key) * 8);
      *(uint4*)dst = make_uint4(v[0], v[1], v[2], v[3]);
    }
  }
}

// ---------------------------------------------------------------------------
// Kernel B (round-7 verbatim except swizzled read): fused masked-softmax +
// PV. Block = 512 thr = 8 waves, each wave = 16 i-rows x ALL 4 heads. j is
// block-resident: block owns JL=512 j, staged as 2 slabs of 256 j x 256
// channels (128KB LDS) -- 4 barriers per block total. Within a phase:
// 8 chunks of 32 j, fully unrolled, adj register-prefetched 1 chunk ahead.
// CHANGED: B-frag read uses 3-bit swizzle pos = (K>>1)*64 +
// ((((K&1)*4+lg) ^ (l15&7))*8)  -> 8-way bank spread (2 lanes/slot = free).
// ---------------------------------------------------------------------------
__global__ __launch_bounds__(512, 2) void k_gat(
    const int* __restrict__ adj, const unsigned short* __restrict__ hT,
    const float* __restrict__ el_t, const u32* __restrict__ QS,
    const unsigned* __restrict__ M_enc,
    _Float16* __restrict__ nump, float* __restrict__ denp)
{
  __shared__ __align__(16) unsigned short hbuf[256 * 256];  // 128KB [256 c][256 j]
  __shared__ __align__(16) u32 qsb[4 * JL];                 // 8KB [4 h][512 j]

  const int tid = threadIdx.x;
  const int wid = tid >> 6, lane = tid & 63;
  const int l15 = lane & 15, lg = lane >> 4;
  const int i0 = blockIdx.x * 128 + wid * 16;
  const int js = blockIdx.y;
  const int j0 = js * JL;
  const int key = l15 & 7;

  float P[4], R[4];
#pragma unroll
  for (int h = 0; h < 4; ++h) {
    float el  = el_t[h * NNODES + i0 + l15];
    float M   = decf(M_enc[h]);
    float sE  = el + M;
    float mih = fmaxf(sE, NEG * sE);   // >= every masked score for row i
    P[h] = __expf(el - mih);
    R[h] = __expf(NEG * el - mih);
  }

  // QS staged once (both phases): 8 waves x 1KB
  __builtin_amdgcn_global_load_lds(
      QS + (size_t)(wid >> 1) * NNODES + j0 + (wid & 1) * 256 + lane * 4,
      qsb + (wid >> 1) * JL + (wid & 1) * 256, 16, 0, 0);

  const int* asrc = adj + (size_t)(i0 + l15) * NNODES + j0 + lg * 8;

  f32x4 acc[4][4];
  f32x4 accd[4];
#pragma unroll
  for (int h = 0; h < 4; ++h) {
    accd[h] = (f32x4){0.f, 0.f, 0.f, 0.f};
#pragma unroll
    for (int c = 0; c < 4; ++c) acc[h][c] = (f32x4){0.f, 0.f, 0.f, 0.f};
  }
  s16x8 ones;
#pragma unroll
  for (int e = 0; e < 8; ++e) ones[e] = (short)0x3F80;  // bf16 1.0

  // stage hT slab for phase p: 16 x 1KB instrs/wave (2 c-rows each)
#define STAGE(p)                                                                 \
  do {                                                                           \
    _Pragma("unroll")                                                            \
    for (int q = 0; q < 16; ++q) {                                               \
      const int c2 = wid * 32 + q * 2;                                           \
      __builtin_amdgcn_global_load_lds(                                          \
          hT + (size_t)(c2 + (lane >> 5)) * NNODES + j0 + (p) * 256 + (lane & 31) * 8, \
          hbuf + c2 * 256, 16, 0, 0);                                            \
    }                                                                            \
  } while (0)

  STAGE(0);

#pragma unroll
  for (int p = 0; p < 2; ++p) {
    if (p == 1) {
      __syncthreads();          // all phase-0 LDS reads done before overwrite
      STAGE(1);
    }
    // prefetch adj chunk 0 of this phase (overlaps staging latency)
    i32x4 a0 = *(const i32x4*)(asrc + p * 256);
    i32x4 a1 = *(const i32x4*)(asrc + p * 256 + 4);
    __syncthreads();            // slab + QS ready (vmcnt drain + barrier)

#pragma unroll
    for (int K = 0; K < 8; ++K) {
      const int nK = (K < 7) ? (K + 1) : 7;
      i32x4 na0 = *(const i32x4*)(asrc + p * 256 + nK * 32);
      i32x4 na1 = *(const i32x4*)(asrc + p * 256 + nK * 32 + 4);

      const int pos = (K >> 1) * 64 + ((((K & 1) * 4 + lg) ^ key) * 8);

#pragma unroll
      for (int h = 0; h < 4; ++h) {
        const unsigned short* lb = hbuf + (h * 64 + l15) * 256 + pos;
        s16x8 b0 = *(const s16x8*)(lb);
        s16x8 b1 = *(const s16x8*)(lb + 16 * 256);
        s16x8 b2 = *(const s16x8*)(lb + 32 * 256);
        s16x8 b3 = *(const s16x8*)(lb + 48 * 256);
        const u32* qrow = qsb + h * JL + p * 256 + K * 32 + lg * 8;
        i32x4 q0 = *(const i32x4*)(qrow);
        i32x4 q1 = *(const i32x4*)(qrow + 4);

        float w[8];
#pragma unroll
        for (int e = 0; e < 4; ++e) {
          u32 m0 = (a0[e] > 0) ? (u32)q0[e] : 0u;
          u32 m1 = (a1[e] > 0) ? (u32)q1[e] : 0u;
          float qq0 = __uint_as_float(m0 << 16);
          float ss0 = __uint_as_float(m0 & 0xffff0000u);
          float qq1 = __uint_as_float(m1 << 16);
          float ss1 = __uint_as_float(m1 & 0xffff0000u);
          w[e]     = fmaxf(P[h] * qq0, R[h] * ss0);
          w[e + 4] = fmaxf(P[h] * qq1, R[h] * ss1);
        }
        union { u32 uu[4]; s16x8 v; } af;
#pragma unroll
        for (int pp = 0; pp < 4; ++pp)
          asm("v_cvt_pk_bf16_f32 %0, %1, %2"
              : "=v"(af.uu[pp]) : "v"(w[2 * pp]), "v"(w[2 * pp + 1]));

        acc[h][0] = __builtin_amdgcn_mfma_f32_16x16x32_bf16(af.v, b0,   acc[h][0], 0, 0, 0);
        acc[h][1] = __builtin_amdgcn_mfma_f32_16x16x32_bf16(af.v, b1,   acc[h][1], 0, 0, 0);
        acc[h][2] = __builtin_amdgcn_mfma_f32_16x16x32_bf16(af.v, b2,   acc[h][2], 0, 0, 0);
        acc[h][3] = __builtin_amdgcn_mfma_f32_16x16x32_bf16(af.v, b3,   acc[h][3], 0, 0, 0);
        accd[h]   = __builtin_amdgcn_mfma_f32_16x16x32_bf16(af.v, ones, accd[h],   0, 0, 0);
      }
      a0 = na0; a1 = na1;
    }
  }
#undef STAGE

  // C/D layout: col = lane&15, row = (lane>>4)*4 + reg
  const int orow = i0 + lg * 4;
#pragma unroll
  for (int h = 0; h < 4; ++h) {
    _Float16* np = nump + ((size_t)js * NNODES + orow) * OUTF + h * 64 + l15;
#pragma unroll
    for (int c = 0; c < 4; ++c)
#pragma unroll
      for (int r = 0; r < 4; ++r)
        np[r * OUTF + c * 16] = (_Float16)acc[h][c][r];
  }
  if (l15 == 0) {
    float* dp = denp + ((size_t)js * NNODES + orow) * 4;
#pragma unroll
    for (int h = 0; h < 4; ++h)
#pragma unroll
      for (int r = 0; r < 4; ++r) dp[r * 4 + h] = accd[h][r];
  }
}

// ---------------------------------------------------------------------------
// Kernel C: sum f16 j-split partials, divide by den, add bias.
// ---------------------------------------------------------------------------
__global__ __launch_bounds__(256) void k_div(
    const _Float16* __restrict__ nump, const float* __restrict__ denp,
    const float* __restrict__ bias, float* __restrict__ out)
{
  const int q  = blockIdx.x * 256 + threadIdx.x;  // float4 index
  const int n  = q >> 6;
  const int c4 = (q & 63) * 4;
  const int h  = c4 >> 6;
  f32x4 s = {0.f, 0.f, 0.f, 0.f};
  float d = 0.f;
#pragma unroll
  for (int t = 0; t < SJ; ++t) {
    f16x4 v = *(const f16x4*)(nump + ((size_t)t * NNODES + n) * OUTF + c4);
    s[0] += (float)v[0]; s[1] += (float)v[1];
    s[2] += (float)v[2]; s[3] += (float)v[3];
    d += denp[((size_t)t * NNODES + n) * 4 + h];
  }
  f32x4 b = *(const f32x4*)(bias + c4);
  float r = __builtin_amdgcn_rcpf(d);
  f32x4 o = s * r + b;
  *(f32x4*)(out + (size_t)n * OUTF + c4) = o;
}

extern "C" void kernel_launch(void* const* d_in, const int* in_sizes, int n_in,
                              void* d_out, int out_size, void* d_ws, size_t ws_size,
                              hipStream_t stream)
{
  const float* x    = (const float*)d_in[0];
  const int*   adj  = (const int*)d_in[1];
  const float* W    = (const float*)d_in[2];
  const float* attl = (const float*)d_in[3];
  const float* attr = (const float*)d_in[4];
  const float* bias = (const float*)d_in[5];
  float* out = (float*)d_out;
  char*  ws  = (char*)d_ws;

  // workspace layout (~19MB)
  unsigned short* hT  = (unsigned short*)ws;                        // 2 MB
  float*     el_t  = (float*)(ws + (2u << 20));                     // 64 KB
  u32*       QS    = (u32*)(ws + (2u << 20) + (64u << 10));         // 64 KB
  unsigned*  M_enc = (unsigned*)(ws + (2u << 20) + (128u << 10));   // 16 B
  float*     denp  = (float*)(ws + (2u << 20) + (192u << 10));      // 512 KB
  _Float16*  nump  = (_Float16*)(ws + (3u << 20));                  // 16 MB

  hipMemsetAsync(M_enc, 0, 16, stream);
  k_feat<<<dim3(4, 64), 256, 0, stream>>>(x, W, attl, attr, hT, el_t, QS, M_enc);
  k_gat<<<dim3(32, SJ), 512, 0, stream>>>(adj, hT, el_t, QS, M_enc, nump, denp);
  k_div<<<dim3(1024), 256, 0, stream>>>(nump, denp, bias, out);
}